// Round 7
// baseline (146.293 us; speedup 1.0000x reference)
//
#include <hip/hip_runtime.h>

#define IMG     256
#define NIMG    384                    // B*C = 128*3
#define STEPS   64
#define ROWS_PW 8                      // rows per wave
#define WAVES   4
#define ROWS_PB (ROWS_PW * WAVES)      // 32 rows per block
#define BANDS   (IMG / ROWS_PB)        // 8 blocks per image -> 3072 blocks
#define NROWS   (ROWS_PW + 2)          // rows held in registers (with halo)
#define NCOPY   (WAVES * 2)            // wave x lane-parity sub-histograms
#define HSTRIDE 65                     // 65-int stride: copy j shifts banks by j
#define INFV    1e30f

// bin = clip(ceil((v-0.02)/RES), 0, 63); fused form ceil(v*65.625 - 1.3125).
// Differs from the reference's f32 divide only on ~ULP bin-boundary values;
// absmax tolerance (174) absorbs that.
__device__ __forceinline__ int bin_of(float v) {
    int t = (int)ceilf(__builtin_fmaf(v, 65.625f, -1.3125f));
    t = t < 0 ? 0 : t;
    return t > 63 ? 63 : t;
}

// Max-vertex attribution: each cell (vertex/edge/square) is attributed to its
// (value, index)-max corner; all cells owned by a pixel share its filtration
// -> one integer LDS-histogram add per pixel.
// Structure: all 10 row loads issued back-to-back (single vmcnt drain per
// wave); every cell-pair compare computed once and reused complemented by the
// other endpoint; histograms split 8 ways (wave x lane-parity) at 65-int
// stride so two parities hitting the SAME bin land on adjacent LDS banks.
__global__ __launch_bounds__(256) void ecc_main(const float* __restrict__ x,
                                                int* __restrict__ hist) {
    const int img  = blockIdx.x / BANDS;
    const int band = blockIdx.x % BANDS;
    const int lane = threadIdx.x & 63;
    const int wave = threadIdx.x >> 6;
    const int col0 = lane * 4;
    const int r0   = band * ROWS_PB + wave * ROWS_PW;

    __shared__ int lh[NCOPY * HSTRIDE];        // 8 copies, 65-int stride
    for (int t = threadIdx.x; t < NCOPY * HSTRIDE; t += 256) lh[t] = 0;
    __syncthreads();
    int* myh = &lh[(wave * 2 + (lane & 1)) * HSTRIDE];

    const float* base = x + (size_t)img * (IMG * IMG);

    // Stage 1: all row loads back-to-back (wave's 64 lanes x 4 cols = one
    // full 256-wide row -> exactly 1 VMEM instruction per row).
    float4 q[NROWS];
#pragma unroll
    for (int k = 0; k < NROWS; ++k) {
        int r = r0 - 1 + k;                    // wave-uniform bounds test
        if ((unsigned)r < IMG) q[k] = *(const float4*)(base + r * IMG + col0);
        else                   q[k] = make_float4(INFV, INFV, INFV, INFV);
    }

    auto halo = [&](int k, float& l, float& r) {
        float lv = __shfl_up(q[k].w, 1, 64);   // lane-1's last element
        float rv = __shfl_down(q[k].x, 1, 64); // lane+1's first element
        l = (lane == 0)  ? INFV : lv;          // lane 0 = image col 0
        r = (lane == 63) ? INFV : rv;          // lane 63 ends at col 255
    };

    // Carried up-row flags (window cols 1..4): pU[i]=(u[i]<=c[i]),
    // pUR[i]=(u[i+1]<=c[i]), pUL[i]=(u[i-1]<=c[i]).
    bool pU[5], pUR[5], pUL[5];
    float chl, chr;                            // halos of current c row
    {
        float uhl, uhr;
        halo(0, uhl, uhr);
        halo(1, chl, chr);
        float u[6] = {uhl, q[0].x, q[0].y, q[0].z, q[0].w, uhr};
        float c[6] = {chl, q[1].x, q[1].y, q[1].z, q[1].w, chr};
#pragma unroll
        for (int i = 1; i <= 4; ++i) {
            pU[i]  = (u[i]     <= c[i]);
            pUR[i] = (u[i + 1] <= c[i]);
            pUL[i] = (u[i - 1] <= c[i]);
        }
    }

#pragma unroll
    for (int k = 1; k <= ROWS_PW; ++k) {
        float dhl, dhr;
        halo(k + 1, dhl, dhr);
        float c[6] = {chl, q[k].x,     q[k].y,     q[k].z,     q[k].w,     chr};
        float d[6] = {dhl, q[k + 1].x, q[k + 1].y, q[k + 1].z, q[k + 1].w, dhr};

        bool eD[5], dDR[5], dDL[5], eR[5];
#pragma unroll
        for (int i = 1; i <= 4; ++i) {
            eD[i]  = (d[i]     < c[i]);        // p owns down edge
            dDR[i] = (d[i + 1] < c[i]);        // down-right diagonal compare
            dDL[i] = (d[i - 1] < c[i]);        // down-left  diagonal compare
            eR[i]  = (c[i + 1] < c[i]);        // p owns right edge
        }
        bool dDRm = (d[1] < c[0]);             // serves next row's pUL[1]
        bool dDLp = (d[4] < c[5]);             // serves next row's pUR[4]
        bool oLn  = (c[0] <= c[1]);            // oL for i=1

#pragma unroll
        for (int i = 1; i <= 4; ++i) {
            float cv = c[i];
            bool oR = eR[i], oL = oLn, oD = eD[i], oU = pU[i];
            bool sDR = oR & oD & dDR[i];
            bool sDL = oL & oD & dDL[i];
            bool sUR = oU & oR & pUR[i];
            bool sUL = oU & oL & pUL[i];
            int contrib = 1 - ((int)oR + (int)oL + (int)oD + (int)oU)
                            + ((int)sDR + (int)sDL + (int)sUR + (int)sUL);
            if (cv <= 0.98f && contrib)        // reference T_MAX mask
                atomicAdd(&myh[bin_of(cv)], contrib);
            oLn = !eR[i];                      // oL(i+1) = !(c[i+1] < c[i])
        }

        // rotate: current down-compares become next row's up-flags (negated)
#pragma unroll
        for (int i = 1; i <= 4; ++i) pU[i] = !eD[i];
        pUR[1] = !dDL[2]; pUR[2] = !dDL[3]; pUR[3] = !dDL[4]; pUR[4] = !dDLp;
        pUL[1] = !dDRm;   pUL[2] = !dDR[1]; pUL[3] = !dDR[2]; pUL[4] = !dDR[3];
        chl = dhl; chr = dhr;
    }

    __syncthreads();
    if (threadIdx.x < STEPS) {
        int t = threadIdx.x;
        int tot = 0;
#pragma unroll
        for (int j = 0; j < NCOPY; ++j) tot += lh[j * HSTRIDE + t];
        // plain store to this block's private slot (d_ws is 0xAA-poisoned,
        // so write unconditionally, zeros included)
        hist[blockIdx.x * STEPS + t] = tot;
    }
}

// 4 images per 256-thread block: sum 8 band histograms, inclusive shfl scan.
__global__ __launch_bounds__(256) void ecc_scan(const int* __restrict__ hist,
                                                float* __restrict__ out) {
    const int img = blockIdx.x * 4 + (threadIdx.x >> 6);
    const int t   = threadIdx.x & 63;
    int v = 0;
#pragma unroll
    for (int b = 0; b < BANDS; ++b)
        v += hist[(img * BANDS + b) * STEPS + t];
#pragma unroll
    for (int s = 1; s < 64; s <<= 1) {
        int y = __shfl_up(v, s, 64);
        if (t >= s) v += y;
    }
    out[img * STEPS + t] = (float)v;
}

extern "C" void kernel_launch(void* const* d_in, const int* in_sizes, int n_in,
                              void* d_out, int out_size, void* d_ws, size_t ws_size,
                              hipStream_t stream) {
    const float* x = (const float*)d_in[0];
    float* out = (float*)d_out;
    int* hist = (int*)d_ws;                    // NIMG*BANDS*STEPS ints (768 KiB)

    ecc_main<<<dim3(NIMG * BANDS), dim3(256), 0, stream>>>(x, hist);
    ecc_scan<<<dim3(NIMG / 4), dim3(256), 0, stream>>>(hist, out);
}